// Round 1
// baseline (523.187 us; speedup 1.0000x reference)
//
#include <hip/hip_runtime.h>
#include <stdint.h>
#include <float.h>
#include <math.h>

#define TPB 256
#define TOTAL 16368

// order-preserving float->uint key (monotonic increasing)
__device__ __forceinline__ uint32_t fkey(float f) {
    uint32_t u = __float_as_uint(f);
    return (u & 0x80000000u) ? ~u : (u | 0x80000000u);
}
__device__ __forceinline__ float keyf(uint32_t k) {
    uint32_t u = (k & 0x80000000u) ? (k & 0x7FFFFFFFu) : ~k;
    return __uint_as_float(u);
}

__device__ __forceinline__ float block_sum(float v, volatile float* scr) {
    #pragma unroll
    for (int o = 32; o > 0; o >>= 1) v += __shfl_down(v, o, 64);
    int lane = threadIdx.x & 63, wid = threadIdx.x >> 6;
    __syncthreads();
    if (lane == 0) scr[wid] = v;
    __syncthreads();
    return scr[0] + scr[1] + scr[2] + scr[3];
}
__device__ __forceinline__ float block_max(float v, volatile float* scr) {
    #pragma unroll
    for (int o = 32; o > 0; o >>= 1) v = fmaxf(v, __shfl_down(v, o, 64));
    int lane = threadIdx.x & 63, wid = threadIdx.x >> 6;
    __syncthreads();
    if (lane == 0) scr[wid] = v;
    __syncthreads();
    return fmaxf(fmaxf(scr[0], scr[1]), fmaxf(scr[2], scr[3]));
}

__global__ void zero_out_kernel(float* out) { out[0] = 0.f; }

// One block per batch row for one semantic group.
__global__ __launch_bounds__(TPB) void kd_group_kernel(
    const float* __restrict__ sL,   // student logits [1024, 16368]
    const float* __restrict__ tL,   // teacher logits [1024, 16368]
    float* __restrict__ out,        // scalar accumulator
    int C, int k, int off, float scale)
{
    extern __shared__ uint32_t dyn[];
    uint32_t* keys  = dyn;                       // C entries
    float*    slist = (float*)(keys + C);        // 512 entries (k<=500)
    uint32_t* hist  = (uint32_t*)(slist + 512);  // 256 bins
    int*      ties  = (int*)(hist + 256);        // 256 cap
    __shared__ float scr[4];
    __shared__ uint32_t ctrl[2];
    __shared__ int tieCount, sCount, cutIdx;

    const int tid = threadIdx.x;
    const float* t = tL + (size_t)blockIdx.x * TOTAL + off;
    const float* s = sL + (size_t)blockIdx.x * TOTAL + off;

    // load teacher keys into LDS; global max (= max of top-k set)
    float lmax = -FLT_MAX;
    for (int i = tid; i < C; i += TPB) {
        float tv = t[i];
        keys[i] = fkey(tv);
        lmax = fmaxf(lmax, tv);
    }
    const float tmax = block_max(lmax, scr);  // barriers also publish keys

    const bool selAll = (k >= C);
    if (tid == 0) { sCount = 0; tieCount = 0; cutIdx = 0x7FFFFFFF; }
    __syncthreads();

    uint32_t tau = 0u;
    if (!selAll) {
        // ---- exact radix select: tau = key of k-th largest teacher value ----
        uint32_t prefix = 0u, pmask = 0u, rem = (uint32_t)k;
        for (int round = 0; round < 4; ++round) {
            const int shift = 24 - 8 * round;
            for (int b = tid; b < 256; b += TPB) hist[b] = 0u;
            __syncthreads();
            for (int i = tid; i < C; i += TPB) {
                uint32_t key = keys[i];
                if ((key & pmask) == prefix)
                    atomicAdd(&hist[(key >> shift) & 0xFFu], 1u);
            }
            __syncthreads();
            if (tid == 0) {
                uint32_t cum = 0u, bb = 0u, rr = rem;
                for (int b = 255; b >= 0; --b) {
                    uint32_t h = hist[b];
                    if (cum + h >= rem) { bb = (uint32_t)b; rr = rem - cum; break; }
                    cum += h;
                }
                ctrl[0] = bb; ctrl[1] = rr;
            }
            __syncthreads();
            prefix |= ctrl[0] << shift;
            pmask  |= 0xFFu << shift;
            rem     = ctrl[1];
            __syncthreads();
        }
        tau = prefix;
        const int nT = (int)rem;  // # of elements == tau to include (lowest idx first)

        // gather tie indices; replicate lax.top_k lowest-index tie-break
        for (int i = tid; i < C; i += TPB) {
            if (keys[i] == tau) {
                int p = atomicAdd(&tieCount, 1);
                if (p < 256) ties[p] = i;
            }
        }
        __syncthreads();
        if (tid == 0) {
            if (tieCount > nT) {   // need only the nT smallest tie indices
                int m = tieCount < 256 ? tieCount : 256;
                int cut = -1;
                for (int selc = 0; selc < nT; ++selc) {
                    int best = 0x7FFFFFFF;
                    for (int j = 0; j < m; ++j) {
                        int v = ties[j];
                        if (v > cut && v < best) best = v;
                    }
                    cut = best;
                }
                cutIdx = cut;
            } // else keep INT_MAX: include all ties
        }
        __syncthreads();
    }

    // ---- pass A: teacher-weighted sums over included set; stash s values ----
    const int cut = cutIdx;
    float St = 0.f, Stt = 0.f, Sts = 0.f, lsmax = -FLT_MAX;
    for (int i = tid; i < C; i += TPB) {
        uint32_t key = keys[i];
        bool inc = selAll || (key > tau) || (key == tau && i <= cut);
        if (inc) {
            float tv = keyf(key);
            float sv = s[i];
            float e = __expf(tv - tmax);
            St  += e;
            Stt += e * tv;
            Sts += e * sv;
            lsmax = fmaxf(lsmax, sv);
            int p = atomicAdd(&sCount, 1);  // p < k <= 500 < 512 guaranteed
            slist[p] = sv;
        }
    }
    St  = block_sum(St, scr);
    Stt = block_sum(Stt, scr);
    Sts = block_sum(Sts, scr);
    const float smax = block_max(lsmax, scr);

    // ---- pass B: student logsumexp over included set ----
    const int n = sCount;
    float Ss = 0.f;
    for (int j = tid; j < n; j += TPB) Ss += __expf(slist[j] - smax);
    Ss = block_sum(Ss, scr);

    if (tid == 0) {
        // KL = sum q*(log q - log p) = (Stt - Sts)/St - (tmax+log St) + (smax+log Ss)
        float kl = (Stt - Sts) / St - tmax - logf(St) + smax + logf(Ss);
        atomicAdd(out, kl * scale);
    }
}

extern "C" void kernel_launch(void* const* d_in, const int* in_sizes, int n_in,
                              void* d_out, int out_size, void* d_ws, size_t ws_size,
                              hipStream_t stream) {
    (void)in_sizes; (void)n_in; (void)d_ws; (void)ws_size; (void)out_size;
    const float* s = (const float*)d_in[0];
    const float* t = (const float*)d_in[1];
    // d_in[2] (targets) is dead code in the reference
    float* out = (float*)d_out;

    hipLaunchKernelGGL(zero_out_kernel, dim3(1), dim3(1), 0, stream, out);

    static const int gs[10] = {8192, 4096, 2048, 1024, 512, 256, 128, 64, 32, 16};
    const float scale = 0.1f / 1024.f;  // norm_factor / batch, T=1
    int off = 0;
    for (int g = 0; g < 10; ++g) {
        const int C = gs[g];
        const int k = C < 500 ? C : 500;
        const size_t shmem = (size_t)C * 4 + 512 * 4 + 256 * 4 + 256 * 4;
        hipLaunchKernelGGL(kd_group_kernel, dim3(1024), dim3(TPB), shmem, stream,
                           s, t, out, C, k, off, scale);
        off += C;
    }
}

// Round 2
// 285.375 us; speedup vs baseline: 1.8333x; 1.8333x over previous
//
#include <hip/hip_runtime.h>
#include <stdint.h>
#include <float.h>
#include <math.h>

#define TPB 256
#define TOTAL 16368

__constant__ int c_gs[10]   = {8192,4096,2048,1024,512,256,128,64,32,16};
__constant__ int c_offs[10] = {0,8192,12288,14336,15360,15872,16128,16256,16320,16352};

// order-preserving float->uint key (monotonic increasing)
__device__ __forceinline__ uint32_t fkey(float f) {
    uint32_t u = __float_as_uint(f);
    return (u & 0x80000000u) ? ~u : (u | 0x80000000u);
}

__device__ __forceinline__ float block_max_bcast(float v, float* scr) {
    #pragma unroll
    for (int o = 32; o > 0; o >>= 1) v = fmaxf(v, __shfl_down(v, o, 64));
    __syncthreads();
    if ((threadIdx.x & 63) == 0) scr[threadIdx.x >> 6] = v;
    __syncthreads();
    return fmaxf(fmaxf(scr[0], scr[1]), fmaxf(scr[2], scr[3]));
}

__device__ __forceinline__ void block_sum3(float& a, float& b, float& c, float* scr) {
    #pragma unroll
    for (int o = 32; o > 0; o >>= 1) {
        a += __shfl_down(a, o, 64);
        b += __shfl_down(b, o, 64);
        c += __shfl_down(c, o, 64);
    }
    __syncthreads();
    if ((threadIdx.x & 63) == 0) {
        int w = threadIdx.x >> 6;
        scr[w] = a; scr[4 + w] = b; scr[8 + w] = c;
    }
    __syncthreads();
    a = scr[0] + scr[1] + scr[2] + scr[3];
    b = scr[4] + scr[5] + scr[6] + scr[7];
    c = scr[8] + scr[9] + scr[10] + scr[11];
}

// merge two online-logsumexp states; all values finite (-FLT_MAX sentinel), no NaN
__device__ __forceinline__ void lse_merge(float& m, float& l, float m2, float l2) {
    float M = fmaxf(m, m2);
    l = l * __expf(m - M) + l2 * __expf(m2 - M);
    m = M;
}

__device__ __forceinline__ void block_lse(float& m, float& l, float* scr) {
    #pragma unroll
    for (int o = 32; o > 0; o >>= 1) {
        float m2 = __shfl_down(m, o, 64);
        float l2 = __shfl_down(l, o, 64);
        lse_merge(m, l, m2, l2);
    }
    __syncthreads();
    if ((threadIdx.x & 63) == 0) {
        int w = threadIdx.x >> 6;
        scr[w] = m; scr[4 + w] = l;
    }
    __syncthreads();
    if (threadIdx.x == 0) {
        m = scr[0]; l = scr[4];
        lse_merge(m, l, scr[1], scr[5]);
        lse_merge(m, l, scr[2], scr[6]);
        lse_merge(m, l, scr[3], scr[7]);
    }
}

__global__ void zero_out_kernel(float* out) { out[0] = 0.f; }

// Radix-select groups (C in {8192..512}, k=500). Teacher values live in
// registers (ITEMS per thread); per-wave privatized histograms; parallel
// suffix scan; online-logsumexp for the student (no compaction list).
template <int ITEMS>
__device__ void radix_path(const float* __restrict__ t, const float* __restrict__ s,
                           float* __restrict__ out, float scale,
                           uint32_t* histAll, uint32_t* comb, int* ties,
                           uint32_t* ctrl, int* tieCount, int* cutIdx, float* scr) {
    const int tid = threadIdx.x;
    const uint32_t k = 500u;

    float tv[ITEMS];
    #pragma unroll
    for (int j = 0; j < ITEMS; ++j) tv[j] = t[tid + j * TPB];
    float lmax = -FLT_MAX;
    #pragma unroll
    for (int j = 0; j < ITEMS; ++j) lmax = fmaxf(lmax, tv[j]);
    const float tmax = block_max_bcast(lmax, scr);

    // ---- exact radix select: tau = key of k-th largest teacher value ----
    uint32_t prefix = 0u, pmask = 0u, rem = k;
    for (int round = 0; round < 4; ++round) {
        const int shift = 24 - 8 * round;
        #pragma unroll
        for (int b = tid; b < 1024; b += TPB) histAll[b] = 0u;
        __syncthreads();
        uint32_t* hist = histAll + ((tid >> 6) << 8);  // per-wave private
        #pragma unroll
        for (int j = 0; j < ITEMS; ++j) {
            uint32_t key = fkey(tv[j]);
            if ((key & pmask) == prefix) atomicAdd(&hist[(key >> shift) & 255u], 1u);
        }
        __syncthreads();
        // combine 4 wave-hists, then inclusive suffix scan (ping-pong)
        uint32_t v = histAll[tid] + histAll[tid + 256] + histAll[tid + 512] + histAll[tid + 768];
        uint32_t* cur = comb;
        uint32_t* nxt = comb + 256;
        cur[tid] = v;
        __syncthreads();
        #pragma unroll
        for (int d = 1; d < 256; d <<= 1) {
            uint32_t x = cur[tid] + ((tid + d < 256) ? cur[tid + d] : 0u);
            nxt[tid] = x;
            __syncthreads();
            uint32_t* tmp = cur; cur = nxt; nxt = tmp;
        }
        // cur[b] = #candidates with digit >= b (non-increasing); unique crossing
        uint32_t mine  = cur[tid];
        uint32_t above = (tid < 255) ? cur[tid + 1] : 0u;
        if (mine >= rem && above < rem) { ctrl[0] = (uint32_t)tid; ctrl[1] = rem - above; }
        __syncthreads();
        prefix |= ctrl[0] << shift;
        pmask  |= 0xFFu << shift;
        rem = ctrl[1];
        __syncthreads();
    }
    const uint32_t tau = prefix;
    const int nT = (int)rem;  // # ties at tau to include (lowest index first)

    if (tid == 0) { *tieCount = 0; *cutIdx = 0x7FFFFFFF; }
    __syncthreads();
    #pragma unroll
    for (int j = 0; j < ITEMS; ++j) {
        if (fkey(tv[j]) == tau) {
            int p = atomicAdd(tieCount, 1);
            if (p < 512) ties[p] = tid + j * TPB;
        }
    }
    __syncthreads();
    if (tid == 0 && *tieCount > nT) {
        int m = *tieCount; if (m > 512) m = 512;
        int cut = -1;
        for (int sel = 0; sel < nT; ++sel) {
            int best = 0x7FFFFFFF;
            for (int j2 = 0; j2 < m; ++j2) {
                int vv = ties[j2];
                if (vv > cut && vv < best) best = vv;
            }
            cut = best;
        }
        *cutIdx = cut;
    }
    __syncthreads();
    const int cut = *cutIdx;

    // ---- single pass: teacher-weighted sums + student online logsumexp ----
    float St = 0.f, Stt = 0.f, Sts = 0.f, m = -FLT_MAX, l = 0.f;
    #pragma unroll
    for (int j = 0; j < ITEMS; ++j) {
        uint32_t key = fkey(tv[j]);
        int i = tid + j * TPB;
        bool inc = (key > tau) || (key == tau && i <= cut);
        if (inc) {
            float e = __expf(tv[j] - tmax);
            float sv = s[i];
            St += e; Stt += e * tv[j]; Sts += e * sv;
            if (sv > m) { l = l * __expf(m - sv) + 1.f; m = sv; }
            else        { l += __expf(sv - m); }
        }
    }
    block_sum3(St, Stt, Sts, scr);
    block_lse(m, l, scr);
    if (tid == 0) {
        // KL = (Stt - Sts)/St - (tmax + log St) + (smax + log Ss)
        float kl = (Stt - Sts) / St - tmax - __logf(St) + m + __logf(l);
        atomicAdd(out, kl * scale);
    }
}

// Whole-group path (C <= 256 => k = C): plain dual logsumexp, 1 elem/thread.
__device__ void small_path(int C, const float* __restrict__ t, const float* __restrict__ s,
                           float* __restrict__ out, float scale, float* scr) {
    const int tid = threadIdx.x;
    const bool act = tid < C;
    float tv = act ? t[tid] : -FLT_MAX;
    float sv = act ? s[tid] : -FLT_MAX;
    const float tmax = block_max_bcast(tv, scr);
    float e   = act ? __expf(tv - tmax) : 0.f;
    float St  = e;
    float Stt = act ? e * tv : 0.f;
    float Sts = act ? e * sv : 0.f;
    block_sum3(St, Stt, Sts, scr);
    float m = sv, l = act ? 1.f : 0.f;
    block_lse(m, l, scr);
    if (tid == 0) {
        float kl = (Stt - Sts) / St - tmax - __logf(St) + m + __logf(l);
        atomicAdd(out, kl * scale);
    }
}

__global__ __launch_bounds__(TPB) void kd_all(const float* __restrict__ sL,
                                              const float* __restrict__ tL,
                                              float* __restrict__ out) {
    __shared__ uint32_t histAll[1024];  // 4 wave-private 256-bin hists
    __shared__ uint32_t comb[512];      // suffix-scan ping-pong
    __shared__ int      ties[512];
    __shared__ uint32_t ctrl[2];
    __shared__ int      tieCount, cutIdx;
    __shared__ float    scr[16];

    const int g   = blockIdx.y;
    const int C   = c_gs[g];
    const int off = c_offs[g];
    const float* t = tL + (size_t)blockIdx.x * TOTAL + off;
    const float* s = sL + (size_t)blockIdx.x * TOTAL + off;
    const float scale = 0.1f / 1024.f;  // norm_factor / batch, T=1

    switch (C) {
        case 8192: radix_path<32>(t, s, out, scale, histAll, comb, ties, ctrl, &tieCount, &cutIdx, scr); break;
        case 4096: radix_path<16>(t, s, out, scale, histAll, comb, ties, ctrl, &tieCount, &cutIdx, scr); break;
        case 2048: radix_path<8>(t, s, out, scale, histAll, comb, ties, ctrl, &tieCount, &cutIdx, scr); break;
        case 1024: radix_path<4>(t, s, out, scale, histAll, comb, ties, ctrl, &tieCount, &cutIdx, scr); break;
        case 512:  radix_path<2>(t, s, out, scale, histAll, comb, ties, ctrl, &tieCount, &cutIdx, scr); break;
        default:   small_path(C, t, s, out, scale, scr); break;
    }
}

extern "C" void kernel_launch(void* const* d_in, const int* in_sizes, int n_in,
                              void* d_out, int out_size, void* d_ws, size_t ws_size,
                              hipStream_t stream) {
    (void)in_sizes; (void)n_in; (void)d_ws; (void)ws_size; (void)out_size;
    const float* s = (const float*)d_in[0];
    const float* t = (const float*)d_in[1];
    float* out = (float*)d_out;

    hipLaunchKernelGGL(zero_out_kernel, dim3(1), dim3(1), 0, stream, out);
    hipLaunchKernelGGL(kd_all, dim3(1024, 10), dim3(TPB), 0, stream, s, t, out);
}

// Round 3
// 209.421 us; speedup vs baseline: 2.4983x; 1.3627x over previous
//
#include <hip/hip_runtime.h>
#include <stdint.h>
#include <float.h>
#include <math.h>

#define TPB 256
#define TOTAL 16368
#define K_CAP 500
#define NBUCKET 64

// bracket guesses: z = Phi^-1(1 - 500/C) +/- safety margin (order-stat sd * ~8)
__constant__ float c_zlo[5] = {1.346f, 0.960f, 0.490f, -0.220f, -2.700f};
__constant__ float c_zhi[5] = {1.746f, 1.370f, 0.900f,  0.280f, -1.350f};

// order-preserving float<->uint key (monotonic increasing)
__device__ __forceinline__ uint32_t fkey(float f) {
    uint32_t u = __float_as_uint(f);
    return (u & 0x80000000u) ? ~u : (u | 0x80000000u);
}
__device__ __forceinline__ float keyf(uint32_t k) {
    uint32_t u = (k & 0x80000000u) ? (k & 0x7FFFFFFFu) : ~k;
    return __uint_as_float(u);
}
__device__ __forceinline__ uint32_t uclamp(uint32_t v, uint32_t lo, uint32_t hi) {
    return v < lo ? lo : (v > hi ? hi : v);
}

// ---- block reductions (256 thr = 4 waves), tiny LDS scratch ----
__device__ __forceinline__ void block_stats(float& sum, float& sq, float& mx, float* scrf) {
    #pragma unroll
    for (int o = 32; o > 0; o >>= 1) {
        sum += __shfl_down(sum, o, 64);
        sq  += __shfl_down(sq,  o, 64);
        mx   = fmaxf(mx, __shfl_down(mx, o, 64));
    }
    if ((threadIdx.x & 63) == 0) {
        int w = threadIdx.x >> 6;
        scrf[w] = sum; scrf[4 + w] = sq; scrf[8 + w] = mx;
    }
    __syncthreads();
    sum = scrf[0] + scrf[1] + scrf[2] + scrf[3];
    sq  = scrf[4] + scrf[5] + scrf[6] + scrf[7];
    mx  = fmaxf(fmaxf(scrf[8], scrf[9]), fmaxf(scrf[10], scrf[11]));
}

// one barrier per call; caller alternates slot (8 or 12) -> safe ping-pong
__device__ __forceinline__ int block_count(int c, int* scri, int slot) {
    #pragma unroll
    for (int o = 32; o > 0; o >>= 1) c += __shfl_down(c, o, 64);
    if ((threadIdx.x & 63) == 0) scri[slot + (threadIdx.x >> 6)] = c;
    __syncthreads();
    return scri[slot] + scri[slot + 1] + scri[slot + 2] + scri[slot + 3];
}

__device__ __forceinline__ void block_count2(int a, int b, int* scri, int& oa, int& ob) {
    #pragma unroll
    for (int o = 32; o > 0; o >>= 1) {
        a += __shfl_down(a, o, 64);
        b += __shfl_down(b, o, 64);
    }
    if ((threadIdx.x & 63) == 0) {
        int w = threadIdx.x >> 6;
        scri[w] = a; scri[4 + w] = b;
    }
    __syncthreads();
    oa = scri[0] + scri[1] + scri[2] + scri[3];
    ob = scri[4] + scri[5] + scri[6] + scri[7];
}

__device__ __forceinline__ void block_sum3(float& a, float& b, float& c, float* scrf) {
    #pragma unroll
    for (int o = 32; o > 0; o >>= 1) {
        a += __shfl_down(a, o, 64);
        b += __shfl_down(b, o, 64);
        c += __shfl_down(c, o, 64);
    }
    if ((threadIdx.x & 63) == 0) {
        int w = threadIdx.x >> 6;
        scrf[w] = a; scrf[4 + w] = b; scrf[8 + w] = c;
    }
    __syncthreads();
    a = scrf[0] + scrf[1] + scrf[2] + scrf[3];
    b = scrf[4] + scrf[5] + scrf[6] + scrf[7];
    c = scrf[8] + scrf[9] + scrf[10] + scrf[11];
}

__device__ __forceinline__ void lse_merge(float& m, float& l, float m2, float l2) {
    float M = fmaxf(m, m2);
    l = l * __expf(m - M) + l2 * __expf(m2 - M);
    m = M;
}

__device__ __forceinline__ void block_lse(float& m, float& l, float* scrf) {
    #pragma unroll
    for (int o = 32; o > 0; o >>= 1) {
        float m2 = __shfl_down(m, o, 64);
        float l2 = __shfl_down(l, o, 64);
        lse_merge(m, l, m2, l2);
    }
    if ((threadIdx.x & 63) == 0) {
        int w = threadIdx.x >> 6;
        scrf[12 + w] = m; scrf[16 + w] = l;
    }
    __syncthreads();
    if (threadIdx.x == 0) {
        m = scrf[12]; l = scrf[16];
        lse_merge(m, l, scrf[13], scrf[17]);
        lse_merge(m, l, scrf[14], scrf[18]);
        lse_merge(m, l, scrf[15], scrf[19]);
    }
}

// ---- big-group path: key-space bisection select, values in registers ----
template <int ITEMS4, int C4>
__device__ void bisect_path(const float* __restrict__ t, const float* __restrict__ s,
                            float zlo, float zhi, float* __restrict__ partial,
                            float* scrf, int* scri) {
    const int tid = threadIdx.x;
    const int C = C4 * 4;
    const float4* t4 = (const float4*)t;
    const float QNAN = __uint_as_float(0x7FC00000u);

    float4 v[ITEMS4];
    float sum = 0.f, sq = 0.f, mx = -FLT_MAX;
    #pragma unroll
    for (int j = 0; j < ITEMS4; ++j) {
        int i4 = tid + j * TPB;
        if (i4 < C4) {
            float4 x = t4[i4];
            v[j] = x;
            sum += (x.x + x.y) + (x.z + x.w);
            sq  += x.x * x.x + x.y * x.y + x.z * x.z + x.w * x.w;
            mx = fmaxf(fmaxf(fmaxf(x.x, x.y), fmaxf(x.z, x.w)), mx);
        } else {
            v[j] = make_float4(QNAN, QNAN, QNAN, QNAN);  // fails all compares
        }
    }
    block_stats(sum, sq, mx, scrf);
    const float tmax = mx;
    const float mean = sum / (float)C;
    const float sd = sqrtf(fmaxf(sq / (float)C - mean * mean, 0.f)) + 1e-20f;

    const uint32_t LOK = 0x007FFFFFu;  // key(-inf)
    const uint32_t HIK = 0xFF800000u;  // key(+inf)
    uint32_t g1 = uclamp(fkey(mean + zlo * sd), LOK + 1, HIK - 2);
    uint32_t g2 = uclamp(fkey(mean + zhi * sd), g1 + 1, HIK - 1);
    const float g1f = keyf(g1), g2f = keyf(g2);

    int c1 = 0, c2 = 0;
    #pragma unroll
    for (int j = 0; j < ITEMS4; ++j) {
        float4 x = v[j];
        c1 += (x.x > g1f) + (x.y > g1f) + (x.z > g1f) + (x.w > g1f);
        c2 += (x.x > g2f) + (x.y > g2f) + (x.z > g2f) + (x.w > g2f);
    }
    block_count2(c1, c2, scri, c1, c2);  // slots 0..7 (used once)

    float tau_f = 0.f;
    int cut = -1;             // -1: no ties included (exact-count exit)
    bool done = false;
    if (c1 == K_CAP)      { tau_f = g1f; done = true; }
    else if (c2 == K_CAP) { tau_f = g2f; done = true; }

    if (!done) {
        uint32_t lo = LOK, hi = HIK;
        int cl = C, ch = 0;
        if (c2 >= K_CAP)      { lo = g2; cl = c2; }
        else if (c1 >= K_CAP) { lo = g1; cl = c1; hi = g2; ch = c2; }
        else                  { hi = g1; ch = c1; }

        int par = 0;
        for (int it = 0; it < 72 && (hi - lo) > 1u; ++it) {
            uint32_t mid;
            if (it & 1) {
                mid = lo + ((hi - lo) >> 1);
            } else {  // false position on the empirical CDF
                uint64_t span = hi - lo;
                uint64_t step = span * (uint64_t)(cl - K_CAP) / (uint64_t)(cl - ch);
                if (step < 1) step = 1;
                if (step > span - 1) step = span - 1;
                mid = lo + (uint32_t)step;
            }
            const float mf = keyf(mid);
            int c = 0;
            #pragma unroll
            for (int j = 0; j < ITEMS4; ++j) {
                float4 x = v[j];
                c += (x.x > mf) + (x.y > mf) + (x.z > mf) + (x.w > mf);
            }
            c = block_count(c, scri, 8 + par); par ^= 4;
            if (c == K_CAP) { tau_f = mf; done = true; break; }  // exact set, no ties
            if (c > K_CAP) { lo = mid; cl = c; } else { hi = mid; ch = c; }
        }
        if (!done) {
            // collapsed: tau is the value at key hi; ch = count strictly greater
            tau_f = keyf(hi);
            const int nT = K_CAP - ch;  // ties to include, lowest index first
            int tc = 0;
            #pragma unroll
            for (int j = 0; j < ITEMS4; ++j) {
                float4 x = v[j];
                tc += (x.x == tau_f) + (x.y == tau_f) + (x.z == tau_f) + (x.w == tau_f);
            }
            int tieCount = block_count(tc, scri, 8 + par); par ^= 4;
            if (tieCount <= nT) {
                cut = 0x7FFFFFFF;  // include all ties
            } else {
                // bisect on index: smallest cut with #{tie & idx<=cut} == nT
                int loI = -1, hiI = C - 1;
                while (hiI - loI > 1) {
                    int midI = (loI + hiI) >> 1;
                    int cc = 0;
                    #pragma unroll
                    for (int j = 0; j < ITEMS4; ++j) {
                        int base = (tid + j * TPB) * 4;
                        float4 x = v[j];
                        cc += (x.x == tau_f && base + 0 <= midI);
                        cc += (x.y == tau_f && base + 1 <= midI);
                        cc += (x.z == tau_f && base + 2 <= midI);
                        cc += (x.w == tau_f && base + 3 <= midI);
                    }
                    cc = block_count(cc, scri, 8 + par); par ^= 4;
                    if (cc >= nT) hiI = midI; else loI = midI;
                }
                cut = hiI;
            }
        }
    }

    // ---- final pass: KL pieces over the selected set ----
    float St = 0.f, Stt = 0.f, Sts = 0.f, m = -FLT_MAX, l = 0.f;
    #pragma unroll
    for (int j = 0; j < ITEMS4; ++j) {
        float4 x = v[j];
        int base = (tid + j * TPB) * 4;
        float xv[4] = {x.x, x.y, x.z, x.w};
        #pragma unroll
        for (int q = 0; q < 4; ++q) {
            float xx = xv[q];
            bool inc = (xx > tau_f) || (xx == tau_f && (base + q) <= cut);
            if (inc) {
                float e = __expf(xx - tmax);
                float sv = s[base + q];
                St += e; Stt += e * xx; Sts += e * sv;
                if (sv > m) { l = l * __expf(m - sv) + 1.f; m = sv; }
                else        { l += __expf(sv - m); }
            }
        }
    }
    block_sum3(St, Stt, Sts, scrf);
    block_lse(m, l, scrf);
    if (tid == 0) {
        float kl = (Stt - Sts) / St - tmax - __logf(St) + m + __logf(l);
        atomicAdd(partial, kl * (0.1f / 1024.f));
    }
}

// ---- small groups (k == C): whole-group softmax, one wave, shuffle-only ----
__device__ void wave_group(const float* __restrict__ t, const float* __restrict__ s,
                           int Cg, float* __restrict__ partial) {
    const int lane = threadIdx.x & 63;
    float tv[4], sv[4];
    #pragma unroll
    for (int q = 0; q < 4; ++q) {
        int i = lane + q * 64;
        bool va = i < Cg;
        tv[q] = va ? t[i] : 0.f;
        sv[q] = va ? s[i] : 0.f;
    }
    float mx = -FLT_MAX;
    #pragma unroll
    for (int q = 0; q < 4; ++q) if (lane + q * 64 < Cg) mx = fmaxf(mx, tv[q]);
    #pragma unroll
    for (int o = 32; o > 0; o >>= 1) mx = fmaxf(mx, __shfl_xor(mx, o, 64));

    float St = 0.f, Stt = 0.f, Sts = 0.f, m = -FLT_MAX, l = 0.f;
    #pragma unroll
    for (int q = 0; q < 4; ++q) {
        if (lane + q * 64 < Cg) {
            float e = __expf(tv[q] - mx);
            St += e; Stt += e * tv[q]; Sts += e * sv[q];
            float x = sv[q];
            if (x > m) { l = l * __expf(m - x) + 1.f; m = x; }
            else       { l += __expf(x - m); }
        }
    }
    #pragma unroll
    for (int o = 32; o > 0; o >>= 1) {
        St  += __shfl_xor(St,  o, 64);
        Stt += __shfl_xor(Stt, o, 64);
        Sts += __shfl_xor(Sts, o, 64);
        float m2 = __shfl_xor(m, o, 64);
        float l2 = __shfl_xor(l, o, 64);
        lse_merge(m, l, m2, l2);
    }
    if (lane == 0) {
        float kl = (Stt - Sts) / St - mx - __logf(St) + m + __logf(l);
        atomicAdd(partial, kl * (0.1f / 1024.f));
    }
}

__global__ __launch_bounds__(TPB) void kd_all(const float* __restrict__ sL,
                                              const float* __restrict__ tL,
                                              float* __restrict__ partial) {
    __shared__ float scrf[20];
    __shared__ int scri[16];
    const int row = blockIdx.x;
    const int g = blockIdx.y;
    const float* tr = tL + (size_t)row * TOTAL;
    const float* sr = sL + (size_t)row * TOTAL;
    float* p = partial + ((row + g * 37) & (NBUCKET - 1));

    switch (g) {
    case 0: bisect_path<8, 2048>(tr,         sr,         c_zlo[0], c_zhi[0], p, scrf, scri); break;
    case 1: bisect_path<4, 1024>(tr + 8192,  sr + 8192,  c_zlo[1], c_zhi[1], p, scrf, scri); break;
    case 2: bisect_path<2,  512>(tr + 12288, sr + 12288, c_zlo[2], c_zhi[2], p, scrf, scri); break;
    case 3: bisect_path<1,  256>(tr + 14336, sr + 14336, c_zlo[3], c_zhi[3], p, scrf, scri); break;
    case 4: bisect_path<1,  128>(tr + 15360, sr + 15360, c_zlo[4], c_zhi[4], p, scrf, scri); break;
    default: {  // 5 tiny groups (C=256..16), one wave each, no barriers
        const int w = threadIdx.x >> 6;
        if (w == 0)      wave_group(tr + 15872, sr + 15872, 256, p);
        else if (w == 1) wave_group(tr + 16128, sr + 16128, 128, p);
        else if (w == 2) { wave_group(tr + 16256, sr + 16256, 64, p);
                           wave_group(tr + 16320, sr + 16320, 32, p); }
        else             wave_group(tr + 16352, sr + 16352, 16, p);
        break;
    }
    }
}

__global__ void zero_ws(float* partial) {
    if (threadIdx.x < NBUCKET) partial[threadIdx.x] = 0.f;
}

__global__ void final_sum(const float* __restrict__ partial, float* __restrict__ out) {
    float v = (threadIdx.x < NBUCKET) ? partial[threadIdx.x] : 0.f;
    #pragma unroll
    for (int o = 32; o > 0; o >>= 1) v += __shfl_down(v, o, 64);
    if (threadIdx.x == 0) out[0] = v;
}

extern "C" void kernel_launch(void* const* d_in, const int* in_sizes, int n_in,
                              void* d_out, int out_size, void* d_ws, size_t ws_size,
                              hipStream_t stream) {
    (void)in_sizes; (void)n_in; (void)ws_size; (void)out_size;
    const float* s = (const float*)d_in[0];
    const float* t = (const float*)d_in[1];
    float* out = (float*)d_out;
    float* partial = (float*)d_ws;

    hipLaunchKernelGGL(zero_ws, dim3(1), dim3(64), 0, stream, partial);
    hipLaunchKernelGGL(kd_all, dim3(1024, 6), dim3(TPB), 0, stream, s, t, partial);
    hipLaunchKernelGGL(final_sum, dim3(1), dim3(64), 0, stream, partial, out);
}

// Round 4
// 202.831 us; speedup vs baseline: 2.5794x; 1.0325x over previous
//
#include <hip/hip_runtime.h>
#include <stdint.h>
#include <float.h>

#define TPB 256
#define TOTAL 16368
#define KSEL 500
#define CAP 2048
#define NBUCKET 64

// order-preserving float<->uint key (monotonic increasing)
__device__ __forceinline__ uint32_t fkey(float f) {
    uint32_t u = __float_as_uint(f);
    return (u & 0x80000000u) ? ~u : (u | 0x80000000u);
}
__device__ __forceinline__ float keyf(uint32_t k) {
    uint32_t u = (k & 0x80000000u) ? (k & 0x7FFFFFFFu) : ~k;
    return __uint_as_float(u);
}
__device__ __forceinline__ uint64_t shfl_down_u64(uint64_t v, int o) {
    uint32_t lo = (uint32_t)v, hi = (uint32_t)(v >> 32);
    lo = __shfl_down(lo, o, 64);
    hi = __shfl_down(hi, o, 64);
    return ((uint64_t)hi << 32) | lo;
}

// one barrier per call; caller alternates slot (8 or 12) -> safe ping-pong
__device__ __forceinline__ int block_count(int c, int* scri, int slot) {
    #pragma unroll
    for (int o = 32; o > 0; o >>= 1) c += __shfl_down(c, o, 64);
    if ((threadIdx.x & 63) == 0) scri[slot + (threadIdx.x >> 6)] = c;
    __syncthreads();
    return scri[slot] + scri[slot + 1] + scri[slot + 2] + scri[slot + 3];
}

__device__ __forceinline__ void block_sum3(float& a, float& b, float& c, float* scrf) {
    #pragma unroll
    for (int o = 32; o > 0; o >>= 1) {
        a += __shfl_down(a, o, 64);
        b += __shfl_down(b, o, 64);
        c += __shfl_down(c, o, 64);
    }
    if ((threadIdx.x & 63) == 0) {
        int w = threadIdx.x >> 6;
        scrf[w] = a; scrf[4 + w] = b; scrf[8 + w] = c;
    }
    __syncthreads();
    a = scrf[0] + scrf[1] + scrf[2] + scrf[3];
    b = scrf[4] + scrf[5] + scrf[6] + scrf[7];
    c = scrf[8] + scrf[9] + scrf[10] + scrf[11];
}

__device__ __forceinline__ void lse_merge(float& m, float& l, float m2, float l2) {
    float M = fmaxf(m, m2);
    l = l * __expf(m - M) + l2 * __expf(m2 - M);
    m = M;
}

__device__ __forceinline__ void block_lse(float& m, float& l, float* scrf) {
    #pragma unroll
    for (int o = 32; o > 0; o >>= 1) {
        float m2 = __shfl_down(m, o, 64);
        float l2 = __shfl_down(l, o, 64);
        lse_merge(m, l, m2, l2);
    }
    if ((threadIdx.x & 63) == 0) {
        int w = threadIdx.x >> 6;
        scrf[12 + w] = m; scrf[16 + w] = l;
    }
    __syncthreads();
    if (threadIdx.x == 0) {
        m = scrf[12]; l = scrf[16];
        lse_merge(m, l, scrf[13], scrf[17]);
        lse_merge(m, l, scrf[14], scrf[18]);
        lse_merge(m, l, scrf[15], scrf[19]);
    }
}

// ---- common tail: exact top-K on <=8 register-resident 64-bit keys/thread ----
// ckey = (fkey(val)<<13) | (8191-idx): value order with lowest-index tie-break,
// keys unique => bisection terminates at count==KSEL, no tie pass needed.
template <int NC>
__device__ void tail(uint64_t (&ck)[NC], int cnt, const float* __restrict__ s,
                     float* __restrict__ partial, int* scri, float* scrf,
                     unsigned long long* scru) {
    const int tid = threadIdx.x;

    uint64_t mn = ~0ull, mx = 0ull;
    #pragma unroll
    for (int j = 0; j < NC; ++j) {
        if (tid + j * TPB < cnt) {
            uint64_t k = ck[j];
            mn = k < mn ? k : mn;
            mx = k > mx ? k : mx;
        }
    }
    #pragma unroll
    for (int o = 32; o > 0; o >>= 1) {
        uint64_t m2 = shfl_down_u64(mn, o);
        uint64_t x2 = shfl_down_u64(mx, o);
        mn = m2 < mn ? m2 : mn;
        mx = x2 > mx ? x2 : mx;
    }
    if ((tid & 63) == 0) { scru[tid >> 6] = mn; scru[4 + (tid >> 6)] = mx; }
    __syncthreads();
    {
        uint64_t a = scru[0], b = scru[1], c = scru[2], d = scru[3];
        mn = a < b ? a : b; mn = scru[2] < mn ? c : mn; mn = d < mn ? d : mn;
        a = scru[4]; b = scru[5]; c = scru[6]; d = scru[7];
        mx = a > b ? a : b; mx = c > mx ? c : mx; mx = d > mx ? d : mx;
    }

    uint64_t lo = mn - 1, hi = mx, tau = lo;
    int cl = cnt, ch = 0;
    if (cnt > KSEL) {
        int par = 0;
        for (int it = 0; it < 96; ++it) {
            uint64_t span = hi - lo;
            if (span <= 1) { tau = lo; break; }
            uint64_t mid;
            if ((it & 1) == 0) {  // false position on empirical CDF
                uint64_t step = span * (uint64_t)(cl - KSEL) / (uint64_t)(cl - ch);
                if (step < 1) step = 1;
                if (step > span - 1) step = span - 1;
                mid = lo + step;
            } else {
                mid = lo + (span >> 1);
            }
            int c = 0;
            #pragma unroll
            for (int j = 0; j < NC; ++j) c += (ck[j] > mid);
            c = block_count(c, scri, 8 + par); par ^= 4;
            if (c == KSEL) { tau = mid; break; }
            if (c > KSEL) { lo = mid; cl = c; } else { hi = mid; ch = c; }
        }
    }
    const float tmax = keyf((uint32_t)(mx >> 13));

    // batched scattered student gather: all loads issued before any use
    bool sel[NC]; float sv[NC];
    #pragma unroll
    for (int j = 0; j < NC; ++j) {
        sel[j] = ck[j] > tau;
        int gi = 8191 - (int)(ck[j] & 8191ull);
        sv[j] = sel[j] ? s[gi] : 0.f;
    }
    float St = 0.f, Stt = 0.f, Sts = 0.f, m = -FLT_MAX, l = 0.f;
    #pragma unroll
    for (int j = 0; j < NC; ++j) {
        if (sel[j]) {
            float tv = keyf((uint32_t)(ck[j] >> 13));
            float e = __expf(tv - tmax);
            float x = sv[j];
            St += e; Stt += e * tv; Sts += e * x;
            if (x > m) { l = l * __expf(m - x) + 1.f; m = x; }
            else       { l += __expf(x - m); }
        }
    }
    block_sum3(St, Stt, Sts, scrf);
    block_lse(m, l, scrf);
    if (tid == 0) {
        float kl = (Stt - Sts) / St - tmax - __logf(St) + m + __logf(l);
        atomicAdd(partial, kl * (0.1f / 1024.f));
    }
}

// exact fallback for arbitrary inputs (never taken for N(0,1) data):
// bisect threshold reading global until count in [KSEL, CAP], push those.
__device__ __noinline__ void slow_rebuild(const float* __restrict__ t, int C,
                                          float* vals, uint16_t* idxs,
                                          int* pcnt, int* scri) {
    const int tid = threadIdx.x;
    const int lane = tid & 63;
    uint64_t lo = 0ull, hi = 0x1FFFFFFFFFFFull;  // >= any 45-bit ckey
    uint64_t thrK = 0ull;
    for (int it = 0; it < 96; ++it) {
        uint64_t mid = lo + ((hi - lo) >> 1);
        int c = 0;
        for (int i = tid; i < C; i += TPB) {
            uint64_t k = ((uint64_t)fkey(t[i]) << 13) | (uint64_t)(8191 - i);
            c += (k > mid);
        }
        c = block_count(c, scri, 8 + ((it & 1) << 2));
        if (c >= KSEL && c <= CAP) { thrK = mid; break; }
        if (c > CAP) lo = mid; else hi = mid;
        thrK = mid;
    }
    if (tid == 0) *pcnt = 0;
    __syncthreads();
    const uint64_t ltmask = (1ull << lane) - 1;
    for (int i = tid; i < C; i += TPB) {
        float x = t[i];
        uint64_t k = ((uint64_t)fkey(x) << 13) | (uint64_t)(8191 - i);
        bool p = k > thrK;
        uint64_t mb = __ballot(p);
        int base = 0;
        if (lane == 0) base = atomicAdd(pcnt, __popcll(mb));
        base = __shfl(base, 0, 64);
        if (p) {
            int pos = base + (int)__popcll(mb & ltmask);
            if (pos < CAP) { vals[pos] = x; idxs[pos] = (uint16_t)i; }
        }
    }
    __syncthreads();
}

// big groups (C=8192/4096): stream once, compact candidates > thr into LDS
template <int ITEMS4>
__device__ void big_path(const float* __restrict__ t, const float* __restrict__ s,
                         float thr, float* vals, uint16_t* idxs, int* pcnt,
                         float* __restrict__ partial, int* scri, float* scrf,
                         unsigned long long* scru) {
    const int tid = threadIdx.x;
    const int lane = tid & 63;
    const float4* t4 = (const float4*)t;

    float4 v[ITEMS4];
    #pragma unroll
    for (int j = 0; j < ITEMS4; ++j) v[j] = t4[tid + j * TPB];
    if (tid == 0) *pcnt = 0;
    __syncthreads();

    const uint64_t ltmask = (1ull << lane) - 1;
    #pragma unroll
    for (int j = 0; j < ITEMS4; ++j) {
        float xs[4] = {v[j].x, v[j].y, v[j].z, v[j].w};
        #pragma unroll
        for (int q = 0; q < 4; ++q) {
            float x = xs[q];
            bool p = x > thr;
            uint64_t mb = __ballot(p);
            int base = 0;
            if (lane == 0) base = atomicAdd(pcnt, __popcll(mb));
            base = __shfl(base, 0, 64);
            if (p) {
                int pos = base + (int)__popcll(mb & ltmask);
                if (pos < CAP) {
                    vals[pos] = x;
                    idxs[pos] = (uint16_t)((tid + j * TPB) * 4 + q);
                }
            }
        }
    }
    __syncthreads();
    int cnt = *pcnt;
    if (cnt < KSEL || cnt > CAP) {   // block-uniform
        slow_rebuild(t, ITEMS4 * TPB * 4, vals, idxs, pcnt, scri);
        cnt = *pcnt;
    }

    uint64_t ck[8];
    #pragma unroll
    for (int j = 0; j < 8; ++j) {
        int p = tid + j * TPB;
        ck[j] = (p < cnt)
            ? (((uint64_t)fkey(vals[p]) << 13) | (uint64_t)(8191 - idxs[p]))
            : 0ull;
    }
    tail<8>(ck, cnt, s, partial, scri, scrf, scru);
}

// mid groups (C=2048/1024/512): all elements are candidates, straight to regs
template <int NC>
__device__ void direct_path(const float* __restrict__ t, const float* __restrict__ s,
                            float* __restrict__ partial, int* scri, float* scrf,
                            unsigned long long* scru) {
    const int tid = threadIdx.x;
    uint64_t ck[NC];
    #pragma unroll
    for (int j = 0; j < NC; ++j) {
        int i = tid + j * TPB;
        float x = t[i];
        ck[j] = ((uint64_t)fkey(x) << 13) | (uint64_t)(8191 - i);
    }
    tail<NC>(ck, NC * TPB, s, partial, scri, scrf, scru);
}

// tiny groups (k == C): whole-group softmax, one wave, shuffle-only
__device__ void wave_group(const float* __restrict__ t, const float* __restrict__ s,
                           int Cg, float* __restrict__ partial) {
    const int lane = threadIdx.x & 63;
    float tv[4], sv[4];
    #pragma unroll
    for (int q = 0; q < 4; ++q) {
        int i = lane + q * 64;
        bool va = i < Cg;
        tv[q] = va ? t[i] : 0.f;
        sv[q] = va ? s[i] : 0.f;
    }
    float mx = -FLT_MAX;
    #pragma unroll
    for (int q = 0; q < 4; ++q) if (lane + q * 64 < Cg) mx = fmaxf(mx, tv[q]);
    #pragma unroll
    for (int o = 32; o > 0; o >>= 1) mx = fmaxf(mx, __shfl_xor(mx, o, 64));

    float St = 0.f, Stt = 0.f, Sts = 0.f, m = -FLT_MAX, l = 0.f;
    #pragma unroll
    for (int q = 0; q < 4; ++q) {
        if (lane + q * 64 < Cg) {
            float e = __expf(tv[q] - mx);
            St += e; Stt += e * tv[q]; Sts += e * sv[q];
            float x = sv[q];
            if (x > m) { l = l * __expf(m - x) + 1.f; m = x; }
            else       { l += __expf(x - m); }
        }
    }
    #pragma unroll
    for (int o = 32; o > 0; o >>= 1) {
        St  += __shfl_xor(St,  o, 64);
        Stt += __shfl_xor(Stt, o, 64);
        Sts += __shfl_xor(Sts, o, 64);
        float m2 = __shfl_xor(m, o, 64);
        float l2 = __shfl_xor(l, o, 64);
        lse_merge(m, l, m2, l2);
    }
    if (lane == 0) {
        float kl = (Stt - Sts) / St - mx - __logf(St) + m + __logf(l);
        atomicAdd(partial, kl * (0.1f / 1024.f));
    }
}

__global__ __launch_bounds__(TPB) void kd_all(const float* __restrict__ sL,
                                              const float* __restrict__ tL,
                                              float* __restrict__ partial) {
    __shared__ float    vals[CAP];     // 8 KiB
    __shared__ uint16_t idxs[CAP];     // 4 KiB
    __shared__ float    scrf[20];
    __shared__ int      scri[16];
    __shared__ unsigned long long scru[8];
    __shared__ int      cnt;

    const int row = blockIdx.x;
    const int g = blockIdx.y;
    const float* tr = tL + (size_t)row * TOTAL;
    const float* sr = sL + (size_t)row * TOTAL;
    float* p = partial + ((row + g * 37) & (NBUCKET - 1));

    // fixed N(0,1) thresholds: expected candidates ~1100, bounds [500,2048]
    // guaranteed exact for any input via slow_rebuild fallback
    switch (g) {
    case 0: big_path<8>(tr,          sr,          1.10f, vals, idxs, &cnt, p, scri, scrf, scru); break;
    case 1: big_path<4>(tr + 8192,   sr + 8192,   0.60f, vals, idxs, &cnt, p, scri, scrf, scru); break;
    case 2: direct_path<8>(tr + 12288, sr + 12288, p, scri, scrf, scru); break;
    case 3: direct_path<4>(tr + 14336, sr + 14336, p, scri, scrf, scru); break;
    case 4: direct_path<2>(tr + 15360, sr + 15360, p, scri, scrf, scru); break;
    default: {  // 5 tiny groups (C=256..16), one wave each, no barriers
        const int w = threadIdx.x >> 6;
        if (w == 0)      wave_group(tr + 15872, sr + 15872, 256, p);
        else if (w == 1) wave_group(tr + 16128, sr + 16128, 128, p);
        else if (w == 2) { wave_group(tr + 16256, sr + 16256, 64, p);
                           wave_group(tr + 16320, sr + 16320, 32, p); }
        else             wave_group(tr + 16352, sr + 16352, 16, p);
        break;
    }
    }
}

__global__ void zero_ws(float* partial) {
    if (threadIdx.x < NBUCKET) partial[threadIdx.x] = 0.f;
}

__global__ void final_sum(const float* __restrict__ partial, float* __restrict__ out) {
    float v = (threadIdx.x < NBUCKET) ? partial[threadIdx.x] : 0.f;
    #pragma unroll
    for (int o = 32; o > 0; o >>= 1) v += __shfl_down(v, o, 64);
    if (threadIdx.x == 0) out[0] = v;
}

extern "C" void kernel_launch(void* const* d_in, const int* in_sizes, int n_in,
                              void* d_out, int out_size, void* d_ws, size_t ws_size,
                              hipStream_t stream) {
    (void)in_sizes; (void)n_in; (void)ws_size; (void)out_size;
    const float* s = (const float*)d_in[0];
    const float* t = (const float*)d_in[1];
    float* out = (float*)d_out;
    float* partial = (float*)d_ws;

    hipLaunchKernelGGL(zero_ws, dim3(1), dim3(64), 0, stream, partial);
    hipLaunchKernelGGL(kd_all, dim3(1024, 6), dim3(TPB), 0, stream, s, t, partial);
    hipLaunchKernelGGL(final_sum, dim3(1), dim3(64), 0, stream, partial, out);
}

// Round 5
// 193.902 us; speedup vs baseline: 2.6982x; 1.0461x over previous
//
#include <hip/hip_runtime.h>
#include <stdint.h>
#include <float.h>

#define TOTAL 16368
#define KSEL 500
#define CAP 1536
#define NSLOT 24          // CAP / 64
#define NBUCKET 64

// order-preserving float<->uint key (monotonic increasing on finite floats)
__device__ __forceinline__ uint32_t fkey(float f) {
    uint32_t u = __float_as_uint(f);
    return (u & 0x80000000u) ? ~u : (u | 0x80000000u);
}
__device__ __forceinline__ float keyf(uint32_t k) {
    uint32_t u = (k & 0x80000000u) ? (k & 0x7FFFFFFFu) : ~k;
    return __uint_as_float(u);
}

__device__ __forceinline__ int wave_sumi(int v) {
    #pragma unroll
    for (int o = 32; o > 0; o >>= 1) v += __shfl_xor(v, o, 64);
    return v;
}
__device__ __forceinline__ float wave_sumf(float v) {
    #pragma unroll
    for (int o = 32; o > 0; o >>= 1) v += __shfl_xor(v, o, 64);
    return v;
}
__device__ __forceinline__ float wave_maxf(float v) {
    #pragma unroll
    for (int o = 32; o > 0; o >>= 1) v = fmaxf(v, __shfl_xor(v, o, 64));
    return v;
}

__device__ __forceinline__ void lse_merge(float& m, float& l, float m2, float l2) {
    float M = fmaxf(m, m2);
    l = l * __expf(m - M) + l2 * __expf(m2 - M);
    m = M;
}

// exact exhaustive fallback (never taken for N(0,1) bench data): wave-level
// bisection on 45-bit combined key (fkey<<13 | (8191-idx)) re-reading global.
__device__ __noinline__ void wave_slow_kl(const float* __restrict__ t,
                                          const float* __restrict__ s, int C,
                                          float* __restrict__ partial) {
    const int lane = threadIdx.x & 63;
    uint64_t lo = 0ull, hi = (1ull << 45), tau = 0ull;
    int cl = C, ch = 0;
    for (int it = 0; it < 100; ++it) {
        uint64_t span = hi - lo;
        if (span <= 1ull) { tau = lo; break; }
        uint64_t mid;
        if (it & 1) mid = lo + (span >> 1);
        else {
            uint64_t st = span * (uint64_t)(cl - KSEL) / (uint64_t)(cl - ch);
            if (st < 1) st = 1;
            if (st > span - 1) st = span - 1;
            mid = lo + st;
        }
        int c = 0;
        for (int i = lane; i < C; i += 64) {
            uint64_t ck = ((uint64_t)fkey(t[i]) << 13) | (uint64_t)(8191 - i);
            c += (ck > mid);
        }
        c = wave_sumi(c);
        if (c == KSEL) { tau = mid; break; }
        if (c > KSEL) { lo = mid; cl = c; } else { hi = mid; ch = c; }
    }
    float tmx = -FLT_MAX;
    for (int i = lane; i < C; i += 64) tmx = fmaxf(tmx, t[i]);
    tmx = wave_maxf(tmx);
    float St = 0.f, Stt = 0.f, Sts = 0.f, sm = -FLT_MAX;
    for (int i = lane; i < C; i += 64) {
        float x = t[i];
        uint64_t ck = ((uint64_t)fkey(x) << 13) | (uint64_t)(8191 - i);
        if (ck > tau) {
            float e = __expf(x - tmx), v = s[i];
            St += e; Stt += e * x; Sts += e * v;
            sm = fmaxf(sm, v);
        }
    }
    St = wave_sumf(St); Stt = wave_sumf(Stt); Sts = wave_sumf(Sts); sm = wave_maxf(sm);
    float Ss = 0.f;
    for (int i = lane; i < C; i += 64) {
        uint64_t ck = ((uint64_t)fkey(t[i]) << 13) | (uint64_t)(8191 - i);
        if (ck > tau) Ss += __expf(s[i] - sm);
    }
    Ss = wave_sumf(Ss);
    if (lane == 0) {
        float kl = (Stt - Sts) / St - tmx - __logf(St) + sm + __logf(Ss);
        atomicAdd(partial, kl * (0.1f / 1024.f));
    }
}

// Exact top-KSEL + KL on register-resident u32 keys (invalid slots: key==0,
// real keys >= 0x00800000). idxOf(j) -> global index within the group.
template <int NS, class IdxF>
__device__ void select_accum(uint32_t (&key)[NS], int nValid, IdxF idxOf,
                             const float* __restrict__ s, float* __restrict__ partial) {
    const int lane = threadIdx.x & 63;
    uint32_t kmx = 0u, kmn = 0xFFFFFFFFu;
    #pragma unroll
    for (int j = 0; j < NS; ++j) {
        uint32_t k = key[j];
        kmx = k > kmx ? k : kmx;
        if (k) kmn = k < kmn ? k : kmn;
    }
    #pragma unroll
    for (int o = 32; o > 0; o >>= 1) {
        uint32_t a = __shfl_xor(kmx, o, 64); kmx = a > kmx ? a : kmx;
        uint32_t b = __shfl_xor(kmn, o, 64); kmn = b < kmn ? b : kmn;
    }
    const float tmax = keyf(kmx);

    uint32_t tauhi; int cut;
    if (nValid == KSEL) { tauhi = kmn - 1u; cut = -1; }
    else {
        uint32_t lo = kmn - 1u, hi = kmx;
        int cl = nValid, ch = 0;
        bool exact = false;
        tauhi = hi; cut = -1;
        // 80 iters: binary every other step => >=40 halvings, span always collapses
        for (int it = 0; it < 80; ++it) {
            uint32_t span = hi - lo;
            if (span <= 1u) break;
            uint32_t mid;
            if (!(it & 1)) {  // false position on empirical CDF
                uint64_t st = (uint64_t)span * (uint32_t)(cl - KSEL) / (uint32_t)(cl - ch);
                if (st < 1) st = 1;
                if (st > span - 1) st = span - 1;
                mid = lo + (uint32_t)st;
            } else mid = lo + (span >> 1);
            int c = 0;
            #pragma unroll
            for (int j = 0; j < NS; ++j) c += (key[j] > mid);
            c = wave_sumi(c);
            if (c == KSEL) { tauhi = mid; cut = -1; exact = true; break; }
            if (c > KSEL) { lo = mid; cl = c; } else { hi = mid; ch = c; }
        }
        if (!exact) {
            tauhi = hi;                      // tied elements have key == hi
            const int nT = KSEL - ch, nTie = cl - ch;
            if (nT >= nTie) cut = 0x7FFFFFFF;
            else {           // lowest-index tie-break: index bisection (rare)
                int l = -1, h = 8191;
                while (h - l > 1) {
                    int m = (l + h) >> 1;
                    int c = 0;
                    #pragma unroll
                    for (int j = 0; j < NS; ++j)
                        c += (key[j] == tauhi && idxOf(j) <= m);
                    c = wave_sumi(c);
                    if (c >= nT) h = m; else l = m;
                }
                cut = h;
            }
        }
    }

    // batched predicated gather, then compute
    uint32_t selm = 0u;
    float sv[NS];
    #pragma unroll
    for (int j = 0; j < NS; ++j) {
        uint32_t kj = key[j];
        bool sj = (kj > tauhi) || (kj == tauhi && idxOf(j) <= cut);
        selm |= (sj ? 1u : 0u) << j;
        sv[j] = sj ? s[idxOf(j)] : 0.f;
    }
    float St = 0.f, Stt = 0.f, Sts = 0.f, sm = -FLT_MAX;
    #pragma unroll
    for (int j = 0; j < NS; ++j) {
        if (selm & (1u << j)) {
            float tv = keyf(key[j]);
            float e = __expf(tv - tmax);
            St += e; Stt += e * tv; Sts += e * sv[j];
            sm = fmaxf(sm, sv[j]);
        }
    }
    #pragma unroll
    for (int o = 32; o > 0; o >>= 1) {
        St  += __shfl_xor(St,  o, 64);
        Stt += __shfl_xor(Stt, o, 64);
        Sts += __shfl_xor(Sts, o, 64);
        sm = fmaxf(sm, __shfl_xor(sm, o, 64));
    }
    float Ss = 0.f;
    #pragma unroll
    for (int j = 0; j < NS; ++j)
        if (selm & (1u << j)) Ss += __expf(sv[j] - sm);
    Ss = wave_sumf(Ss);
    if (lane == 0) {
        float kl = (Stt - Sts) / St - tmax - __logf(St) + sm + __logf(Ss);
        atomicAdd(partial, kl * (0.1f / 1024.f));
    }
}

// mid groups: all C elements live in registers (C = NJ*64; NJ in {32,16,8})
template <int NJ>
__device__ void mid_wave(const float* __restrict__ t, const float* __restrict__ s,
                         float* __restrict__ partial) {
    const int lane = threadIdx.x & 63;
    const float4* t4 = (const float4*)t;
    uint32_t key[NJ];
    #pragma unroll
    for (int c = 0; c < NJ / 4; ++c) {
        float4 x = t4[lane + c * 64];
        key[4 * c + 0] = fkey(x.x); key[4 * c + 1] = fkey(x.y);
        key[4 * c + 2] = fkey(x.z); key[4 * c + 3] = fkey(x.w);
    }
    auto idxOf = [&](int j) { return ((lane + (j >> 2) * 64) << 2) + (j & 3); };
    select_accum<NJ>(key, NJ * 64, idxOf, s, partial);
}

// big groups (C = NJ4*256): stream once, ballot-compact x>thr to per-wave LDS
template <int NJ4>
__device__ void big_wave(const float* __restrict__ t, const float* __restrict__ s,
                         float thr, float* __restrict__ partial,
                         float* vals, uint16_t* idxs) {
    const int lane = threadIdx.x & 63;
    const float4* t4 = (const float4*)t;
    const uint64_t ltm = (1ull << lane) - 1ull;
    int cnt = 0;
    #pragma unroll
    for (int c0 = 0; c0 < NJ4; c0 += 8) {
        float4 buf[8];
        #pragma unroll
        for (int u = 0; u < 8; ++u) buf[u] = t4[(c0 + u) * 64 + lane];
        #pragma unroll
        for (int u = 0; u < 8; ++u) {
            float xs[4] = {buf[u].x, buf[u].y, buf[u].z, buf[u].w};
            #pragma unroll
            for (int q = 0; q < 4; ++q) {
                bool p = xs[q] > thr;
                uint64_t mb = __ballot(p);
                if (p) {
                    int pos = cnt + (int)__popcll(mb & ltm);
                    if (pos < CAP) {
                        vals[pos] = xs[q];
                        idxs[pos] = (uint16_t)((((c0 + u) * 64 + lane) << 2) + q);
                    }
                }
                cnt += (int)__popcll(mb);
            }
        }
    }
    if (cnt < KSEL || cnt > CAP) { wave_slow_kl(t, s, NJ4 * 256, partial); return; }
    uint32_t key[NSLOT], gidx[NSLOT];
    #pragma unroll
    for (int j = 0; j < NSLOT; ++j) {
        int p = lane + j * 64;
        bool v = p < cnt;
        key[j]  = v ? fkey(vals[p]) : 0u;
        gidx[j] = v ? (uint32_t)idxs[p] : 0u;
    }
    auto idxOf = [&](int j) { return (int)gidx[j]; };
    select_accum<NSLOT>(key, cnt, idxOf, s, partial);
}

// tiny groups (k == C): whole-group softmax, shuffle-only
__device__ void tiny_group(const float* __restrict__ t, const float* __restrict__ s,
                           int Cg, float* __restrict__ partial) {
    const int lane = threadIdx.x & 63;
    float St = 0.f, Stt = 0.f, Sts = 0.f, m = -FLT_MAX, l = 0.f;
    float tv[4], svv[4];
    #pragma unroll
    for (int q = 0; q < 4; ++q) {
        int i = lane + q * 64;
        bool va = i < Cg;
        tv[q] = va ? t[i] : -FLT_MAX;
        svv[q] = va ? s[i] : 0.f;
    }
    float mx = -FLT_MAX;
    #pragma unroll
    for (int q = 0; q < 4; ++q) mx = fmaxf(mx, tv[q]);
    mx = wave_maxf(mx);
    #pragma unroll
    for (int q = 0; q < 4; ++q) {
        if (lane + q * 64 < Cg) {
            float e = __expf(tv[q] - mx);
            St += e; Stt += e * tv[q]; Sts += e * svv[q];
            float x = svv[q];
            if (x > m) { l = l * __expf(m - x) + 1.f; m = x; }
            else       { l += __expf(x - m); }
        }
    }
    #pragma unroll
    for (int o = 32; o > 0; o >>= 1) {
        St  += __shfl_xor(St,  o, 64);
        Stt += __shfl_xor(Stt, o, 64);
        Sts += __shfl_xor(Sts, o, 64);
        float m2 = __shfl_xor(m, o, 64);
        float l2 = __shfl_xor(l, o, 64);
        lse_merge(m, l, m2, l2);
    }
    if (lane == 0) {
        float kl = (Stt - Sts) / St - mx - __logf(St) + m + __logf(l);
        atomicAdd(partial, kl * (0.1f / 1024.f));
    }
}

__global__ __launch_bounds__(64, 4) void kd_all(const float* __restrict__ sL,
                                                const float* __restrict__ tL,
                                                float* __restrict__ partial) {
    __shared__ float    vals[CAP];   // 6 KiB (used by y=0,1 only)
    __shared__ uint16_t idxs[CAP];   // 3 KiB
    const int row = blockIdx.x;
    const int y = blockIdx.y;
    const float* tr = tL + (size_t)row * TOTAL;
    const float* sr = sL + (size_t)row * TOTAL;
    float* p = partial + ((row + y * 37) & (NBUCKET - 1));

    // fixed N(0,1) thresholds (mean candidates ~1110, 14+ sd inside [500,1536]);
    // exactness for arbitrary inputs preserved via wave_slow_kl fallback
    switch (y) {
    case 0: big_wave<32>(tr, sr, 1.10f, p, vals, idxs); break;               // C=8192
    case 1: big_wave<16>(tr + 8192, sr + 8192, 0.60f, p, vals, idxs); break; // C=4096
    case 2:
        mid_wave<32>(tr + 12288, sr + 12288, p);   // C=2048
        mid_wave<16>(tr + 14336, sr + 14336, p);   // C=1024
        break;
    default:
        mid_wave<8>(tr + 15360, sr + 15360, p);    // C=512
        tiny_group(tr + 15872, sr + 15872, 256, p);
        tiny_group(tr + 16128, sr + 16128, 128, p);
        tiny_group(tr + 16256, sr + 16256, 64, p);
        tiny_group(tr + 16320, sr + 16320, 32, p);
        tiny_group(tr + 16352, sr + 16352, 16, p);
        break;
    }
}

__global__ void zero_ws(float* partial) {
    if (threadIdx.x < NBUCKET) partial[threadIdx.x] = 0.f;
}

__global__ void final_sum(const float* __restrict__ partial, float* __restrict__ out) {
    float v = (threadIdx.x < NBUCKET) ? partial[threadIdx.x] : 0.f;
    #pragma unroll
    for (int o = 32; o > 0; o >>= 1) v += __shfl_down(v, o, 64);
    if (threadIdx.x == 0) out[0] = v;
}

extern "C" void kernel_launch(void* const* d_in, const int* in_sizes, int n_in,
                              void* d_out, int out_size, void* d_ws, size_t ws_size,
                              hipStream_t stream) {
    (void)in_sizes; (void)n_in; (void)ws_size; (void)out_size;
    const float* s = (const float*)d_in[0];
    const float* t = (const float*)d_in[1];
    float* out = (float*)d_out;
    float* partial = (float*)d_ws;

    hipLaunchKernelGGL(zero_ws, dim3(1), dim3(64), 0, stream, partial);
    hipLaunchKernelGGL(kd_all, dim3(1024, 4), dim3(64), 0, stream, s, t, partial);
    hipLaunchKernelGGL(final_sum, dim3(1), dim3(64), 0, stream, partial, out);
}